// Round 7
// baseline (5220.778 us; speedup 1.0000x reference)
//
#include <hip/hip_runtime.h>
#include <hip/hip_bf16.h>
#include <cstdint>

// ---------------------------------------------------------------------------
// B=32, L=2048, E=256, H=128, C=128. Scan steps j=0..2046 (t=j+1).
// R7: opaque-asm weight loads. R5/R6 (VGPR=124, identical perf) proved the
// compiler re-loads the 160 weight floats from L2 every step — a plain pin
// can't stop re-loading from known read-only addresses. Inline-asm
// global_load_dwordx4 hides the source => values must stay register-resident.
// Arithmetic is bit-identical to R5/R6 (absmax 0.0) — do not touch.
// ---------------------------------------------------------------------------
static constexpr int BB   = 32;
static constexpr int LQ   = 2048;
static constexpr int NSTP = 2047;
static constexpr int EE   = 256;

__device__ __forceinline__ void bar_lds() {
  asm volatile("s_waitcnt lgkmcnt(0)\n\ts_barrier" ::: "memory");
}

__device__ __forceinline__ float4 opaque_load4(const float* p) {
  float4 r;
  asm volatile("global_load_dwordx4 %0, %1, off"
               : "=v"(r) : "v"(p) : "memory");
  return r;
}

// ---------------- Threefry-2x32 (JAX-compatible, verified R3-R6) -----------
__device__ __forceinline__ uint32_t rotl32(uint32_t x, int d) {
  return (x << d) | (x >> (32 - d));
}
__device__ __forceinline__ void tf2x32(uint32_t k0, uint32_t k1,
                                       uint32_t x0, uint32_t x1,
                                       uint32_t& o0, uint32_t& o1) {
  uint32_t ks2 = k0 ^ k1 ^ 0x1BD11BDAu;
  x0 += k0; x1 += k1;
  x0+=x1; x1=rotl32(x1,13); x1^=x0;  x0+=x1; x1=rotl32(x1,15); x1^=x0;
  x0+=x1; x1=rotl32(x1,26); x1^=x0;  x0+=x1; x1=rotl32(x1, 6); x1^=x0;
  x0+=k1; x1+=ks2+1u;
  x0+=x1; x1=rotl32(x1,17); x1^=x0;  x0+=x1; x1=rotl32(x1,29); x1^=x0;
  x0+=x1; x1=rotl32(x1,16); x1^=x0;  x0+=x1; x1=rotl32(x1,24); x1^=x0;
  x0+=ks2; x1+=k0+2u;
  x0+=x1; x1=rotl32(x1,13); x1^=x0;  x0+=x1; x1=rotl32(x1,15); x1^=x0;
  x0+=x1; x1=rotl32(x1,26); x1^=x0;  x0+=x1; x1=rotl32(x1, 6); x1^=x0;
  x0+=k0; x1+=k1+3u;
  x0+=x1; x1=rotl32(x1,17); x1^=x0;  x0+=x1; x1=rotl32(x1,29); x1^=x0;
  x0+=x1; x1=rotl32(x1,16); x1^=x0;  x0+=x1; x1=rotl32(x1,24); x1^=x0;
  x0+=k1; x1+=ks2+4u;
  x0+=x1; x1=rotl32(x1,13); x1^=x0;  x0+=x1; x1=rotl32(x1,15); x1^=x0;
  x0+=x1; x1=rotl32(x1,26); x1^=x0;  x0+=x1; x1=rotl32(x1, 6); x1^=x0;
  x0+=ks2; x1+=k0+5u;
  o0 = x0; o1 = x1;
}

__device__ __forceinline__ float sigm(float x) { return 1.0f / (1.0f + expf(-x)); }

// ---------------- prep: Whc = Wih[:,128:]+Whh; Wcomb/cbias (P1|G1 fused) ---
__global__ void prep_kernel(const float* __restrict__ Wp1,
                            const float* __restrict__ bp1,
                            const float* __restrict__ Wih,
                            const float* __restrict__ Whh,
                            const float* __restrict__ bih,
                            const float* __restrict__ bhh,
                            float* __restrict__ Whc,
                            float* __restrict__ Wcomb,
                            float* __restrict__ cbias) {
  int tid = blockIdx.x * blockDim.x + threadIdx.x;
  int nt  = gridDim.x * blockDim.x;
  for (int p = tid; p < 512 * 128; p += nt) {
    int g = p >> 7, e = p & 127;
    Whc[p] = Wih[g * 256 + 128 + e] + Whh[p];
  }
  for (int p = tid; p < 640 * 128; p += nt) {
    int n = p >> 7, e = p & 127;
    Wcomb[p] = (n < 128) ? Wp1[n * 256 + e] : Wih[(n - 128) * 256 + e];
  }
  for (int n = tid; n < 640; n += nt)
    cbias[n] = (n < 128) ? bp1[n] : (bih[n - 128] + bhh[n - 128]);
}

// ---------------- precompute gumbel perturbations pg[j][b*6+k] -------------
__global__ void gumbel_kernel(float* __restrict__ pg) {
  int idx = blockIdx.x * blockDim.x + threadIdx.x;
  if (idx >= NSTP * 192) return;
  int j = idx / 192, r = idx % 192;
  uint32_t a0, a1, y0, y1;
  tf2x32(0u, 42u, 0u, (uint32_t)j, a0, a1);
  tf2x32(a0, a1, 0u, (uint32_t)r, y0, y1);
  uint32_t bits = y0 ^ y1;
  float f = __uint_as_float((bits >> 9) | 0x3f800000u) - 1.0f;
  float u = fmaxf(f, 1.17549435e-38f);
  double g = -log(-log((double)u));
  pg[idx] = (float)g;
}

// ---------------- fp32 GEMM (unchanged) ------------------------------------
#define TM 128
#define TN 128
#define TKK 8
template <int MODE>
__global__ __launch_bounds__(256) void gemm_kernel(
    const float* __restrict__ A, const float* __restrict__ Bm, int ldb,
    const float* __restrict__ bias, float* __restrict__ C, int ldc,
    int M, int K, int relu, int NS, int c0) {
  int m0 = blockIdx.x * TM;
  int n0 = blockIdx.y * TN;
  int tid = threadIdx.x;
  __shared__ float As[TKK][TM + 4];
  __shared__ float Bs[TKK][TN + 4];

  int srow = tid >> 1;
  int skq  = (tid & 1) * 4;
  int gm   = m0 + srow;
  bool mvalid = gm < M;
  const float* Arow;
  if (MODE == 1) {
    int gmc = mvalid ? gm : 0;
    int bb = gmc / NS, cs = gmc % NS;
    Arow = A + (size_t)(bb * (LQ + 2) + c0 + cs + 2) * EE;
  } else {
    Arow = A + (size_t)gm * K;
  }
  const float* Brow = Bm + (size_t)(n0 + srow) * ldb;

  float acc[8][8] = {};
  int tm = (tid >> 4) * 8;
  int tn = (tid & 15) * 8;

  for (int k0 = 0; k0 < K; k0 += TKK) {
    float4 av = mvalid ? *(const float4*)(Arow + k0 + skq)
                       : make_float4(0.f, 0.f, 0.f, 0.f);
    float4 bv = *(const float4*)(Brow + k0 + skq);
    __syncthreads();
    As[skq + 0][srow] = av.x; As[skq + 1][srow] = av.y;
    As[skq + 2][srow] = av.z; As[skq + 3][srow] = av.w;
    Bs[skq + 0][srow] = bv.x; Bs[skq + 1][srow] = bv.y;
    Bs[skq + 2][srow] = bv.z; Bs[skq + 3][srow] = bv.w;
    __syncthreads();
#pragma unroll
    for (int kk = 0; kk < TKK; kk++) {
      float4 a0 = *(const float4*)&As[kk][tm];
      float4 a1 = *(const float4*)&As[kk][tm + 4];
      float4 b0 = *(const float4*)&Bs[kk][tn];
      float4 b1 = *(const float4*)&Bs[kk][tn + 4];
      float aa[8] = {a0.x, a0.y, a0.z, a0.w, a1.x, a1.y, a1.z, a1.w};
      float bb2[8] = {b0.x, b0.y, b0.z, b0.w, b1.x, b1.y, b1.z, b1.w};
#pragma unroll
      for (int i = 0; i < 8; i++)
#pragma unroll
        for (int jx = 0; jx < 8; jx++) acc[i][jx] += aa[i] * bb2[jx];
    }
  }
#pragma unroll
  for (int i = 0; i < 8; i++) {
    int gm2 = m0 + tm + i;
    if (gm2 >= M) break;
#pragma unroll
    for (int jx = 0; jx < 8; jx++) {
      int gn = n0 + tn + jx;
      float v = acc[i][jx] + bias[gn];
      if (relu) v = fmaxf(v, 0.f);
      C[(size_t)gm2 * ldc + gn] = v;
    }
  }
}

// ---------------- scan v5: v3 + opaque register-resident weights -----------
// exf rows per (b,cs): 6 x [p1(128) | g1(512)] = 3840 floats.
// state: h[32*128] | c[32*128] | lp[32]
__global__ __launch_bounds__(512, 2) void scan5_kernel(
    const float* __restrict__ exf, const float* __restrict__ pg,
    const int* __restrict__ mask, const int* __restrict__ length,
    const float* __restrict__ Wp1, const float* __restrict__ Wp2,
    const float* __restrict__ bp2, const float* __restrict__ Whc,
    float* __restrict__ state, float* __restrict__ out,
    int c0, int NS, int init) {
  const int b = blockIdx.x;
  const int tid = threadIdx.x;
  const int q = tid & 3;        // h-quarter for phase-A dots
  const int gb = tid >> 2;      // 0..127

  __shared__ float EXF[2][3840];
  __shared__ float h_pad[144];      // quarters at stride 36 (bank-spread)
  __shared__ float hh_s[128];
  __shared__ float ghh_s[512];
  __shared__ float scv[8];
  __shared__ float wp2_lds[128];
  __shared__ float gum_lds[2][8];
  __shared__ int   msk_lds[2][8];
  __shared__ int   idx_s;
  __shared__ char  idxb[2048];

  // ---- weights into registers via OPAQUE loads (cannot be re-derived)
  float4 wp1r4[8], wv40[8], wv41[8], wv42[8], wv43[8];
  {
    const float* s0 = Wp1 + (size_t)gb * 256 + 128 + q * 32;
    const float* a0 = Whc + ((size_t)gb + 0) * 128 + q * 32;
    const float* a1 = Whc + ((size_t)gb + 128) * 128 + q * 32;
    const float* a2 = Whc + ((size_t)gb + 256) * 128 + q * 32;
    const float* a3 = Whc + ((size_t)gb + 384) * 128 + q * 32;
#pragma unroll
    for (int i = 0; i < 8; i++) {
      wp1r4[i] = opaque_load4(s0 + 4 * i);
      wv40[i]  = opaque_load4(a0 + 4 * i);
      wv41[i]  = opaque_load4(a1 + 4 * i);
      wv42[i]  = opaque_load4(a2 + 4 * i);
      wv43[i]  = opaque_load4(a3 + 4 * i);
    }
    asm volatile("s_waitcnt vmcnt(0)" ::: "memory");
    __builtin_amdgcn_sched_barrier(0);
  }
  const float bp2v = bp2[0];
  const int len_b = length[b];

  float c_r = 0.f, lp_r = 0.f;
  if (tid < 144) h_pad[tid] = 0.f;
  if (tid < 128) {
    if (!init) h_pad[(tid >> 5) * 36 + (tid & 31)] = state[b * 128 + tid];
    c_r = init ? 0.f : state[4096 + b * 128 + tid];
    wp2_lds[tid] = Wp2[tid];
  }
  if (tid == 0) lp_r = init ? 0.f : state[8192 + b];

  // ---- prologue: stage step 0; prefetch step 1 into regs
  float4 pf0, pf1, pf2;
  float pfg = 0.f; int pfm = 0;
  {
    const float4* e0 = (const float4*)(exf + (size_t)b * NS * 3840);
    ((float4*)EXF[0])[tid] = e0[tid];
    if (tid < 448) ((float4*)EXF[0])[512 + tid] = e0[512 + tid];
    if (tid < 6) {
      gum_lds[0][tid] = pg[(size_t)c0 * 192 + b * 6 + tid];
      msk_lds[0][tid] = mask[((size_t)b * LQ + c0 + 1) * 6 + tid];
    }
    int cs1 = (NS > 1) ? 1 : 0;
    const float4* e1 = (const float4*)(exf + ((size_t)b * NS + cs1) * 3840);
    if (tid >= 64) {
      int i0 = tid - 64;
      pf0 = e1[i0];
      pf1 = e1[448 + i0];
      if (tid < 128) pf2 = e1[896 + i0];
    }
    if (tid >= 384 && tid < 390)
      pfg = pg[(size_t)(c0 + cs1) * 192 + b * 6 + (tid - 384)];
    if (tid >= 390 && tid < 396)
      pfm = mask[((size_t)b * LQ + c0 + cs1 + 1) * 6 + (tid - 390)];
  }
  bar_lds();

  for (int cs = 0; cs < NS; ++cs) {
    const int buf = cs & 1;
    const int nb = buf ^ 1;

    // ---- phase A: h once from LDS; hid_h partial + 4 gate-h partials
    {
      const float4* hp4 = (const float4*)(h_pad + q * 36);
      float hidp = 0.f, p0 = 0.f, p1 = 0.f, p2 = 0.f, p3 = 0.f;
#pragma unroll
      for (int i = 0; i < 8; i++) {
        float4 hv = hp4[i];
        float4 w = wp1r4[i];
        hidp += w.x * hv.x + w.y * hv.y + w.z * hv.z + w.w * hv.w;
        float4 a = wv40[i];
        p0 += a.x * hv.x + a.y * hv.y + a.z * hv.z + a.w * hv.w;
        a = wv41[i];
        p1 += a.x * hv.x + a.y * hv.y + a.z * hv.z + a.w * hv.w;
        a = wv42[i];
        p2 += a.x * hv.x + a.y * hv.y + a.z * hv.z + a.w * hv.w;
        a = wv43[i];
        p3 += a.x * hv.x + a.y * hv.y + a.z * hv.z + a.w * hv.w;
      }
      hidp += __shfl_xor(hidp, 1); hidp += __shfl_xor(hidp, 2);
      p0 += __shfl_xor(p0, 1); p0 += __shfl_xor(p0, 2);
      p1 += __shfl_xor(p1, 1); p1 += __shfl_xor(p1, 2);
      p2 += __shfl_xor(p2, 1); p2 += __shfl_xor(p2, 2);
      p3 += __shfl_xor(p3, 1); p3 += __shfl_xor(p3, 2);
      if (q == 0) {
        hh_s[gb] = hidp;
        ghh_s[gb] = p0; ghh_s[128 + gb] = p1;
        ghh_s[256 + gb] = p2; ghh_s[384 + gb] = p3;
      }
    }
    bar_lds();

    // ---- phase BC: wave 0 scores+samples; waves 1-7 park & prefetch
    if (tid < 64) {
      const int k = tid >> 3, r = tid & 7;
      float s = 0.f;
      if (k < 6) {
        const float* pb = &EXF[buf][k * 640 + r * 16];
        const float* hb = &hh_s[r * 16];
        const float* wb = &wp2_lds[r * 16];
#pragma unroll
        for (int ii = 0; ii < 4; ii++) {
          float4 p = *(const float4*)(pb + ii * 4);
          float4 hh = *(const float4*)(hb + ii * 4);
          float4 w = *(const float4*)(wb + ii * 4);
          s += fmaxf(p.x + hh.x, 0.f) * w.x + fmaxf(p.y + hh.y, 0.f) * w.y +
               fmaxf(p.z + hh.z, 0.f) * w.z + fmaxf(p.w + hh.w, 0.f) * w.w;
        }
      }
      s += __shfl_xor(s, 1);
      s += __shfl_xor(s, 2);
      s += __shfl_xor(s, 4);
      if (k < 6 && r == 0) scv[k] = fmaxf(s + bp2v, 0.f);
      asm volatile("s_waitcnt lgkmcnt(0)" ::: "memory");
      if (tid == 0) {
        float best = -3.4e38f, mx = -1e9f, libest = -1e9f, ssum;
        int bi = 0;
        float lgv[6];
#pragma unroll
        for (int k2 = 0; k2 < 6; k2++) {
          float lg = msk_lds[buf][k2] ? scv[k2] : -1e9f;
          float pt = gum_lds[buf][k2] + lg;
          if (pt > best) { best = pt; bi = k2; libest = lg; }
          mx = fmaxf(mx, lg);
          lgv[k2] = lg;
        }
        ssum = 0.f;
#pragma unroll
        for (int k2 = 0; k2 < 6; k2++) ssum += __expf(lgv[k2] - mx);
        float logp = libest - mx - __logf(ssum);
        if (len_b > c0 + cs + 1) lp_r += logp;
        idx_s = bi;
        idxb[cs] = (char)bi;
      }
    } else {
      int i0 = tid - 64;
      ((float4*)EXF[nb])[i0] = pf0;
      ((float4*)EXF[nb])[448 + i0] = pf1;
      if (tid < 128) ((float4*)EXF[nb])[896 + i0] = pf2;
      if (tid >= 384 && tid < 390) gum_lds[nb][tid - 384] = pfg;
      if (tid >= 390 && tid < 396) msk_lds[nb][tid - 390] = pfm;
      int csp = (cs + 2 < NS) ? cs + 2 : NS - 1;
      const float4* en = (const float4*)(exf + ((size_t)b * NS + csp) * 3840);
      pf0 = en[i0];
      pf1 = en[448 + i0];
      if (tid < 128) pf2 = en[896 + i0];
      if (tid >= 384 && tid < 390)
        pfg = pg[(size_t)(c0 + csp) * 192 + b * 6 + (tid - 384)];
      if (tid >= 390 && tid < 396)
        pfm = mask[((size_t)b * LQ + c0 + csp + 1) * 6 + (tid - 390)];
    }
    bar_lds();

    // ---- phase D: LSTM pointwise (tid<128)
    if (tid < 128) {
      int base = idx_s * 640 + 128 + tid;
      float iv = EXF[buf][base] + ghh_s[tid];
      float fv = EXF[buf][base + 128] + ghh_s[128 + tid];
      float gg = EXF[buf][base + 256] + ghh_s[256 + tid];
      float ov = EXF[buf][base + 384] + ghh_s[384 + tid];
      float c2 = sigm(fv) * c_r + sigm(iv) * tanhf(gg);
      float h2 = sigm(ov) * tanhf(c2);
      c_r = c2;
      h_pad[(tid >> 5) * 36 + (tid & 31)] = h2;
    }
    bar_lds();
  }

  // ---- epilogue
  if (tid < 128) {
    state[b * 128 + tid] = h_pad[(tid >> 5) * 36 + (tid & 31)];
    state[4096 + b * 128 + tid] = c_r;
  }
  if (tid == 0) {
    state[8192 + b] = lp_r;
    out[b] = lp_r;
  }
  for (int i = tid; i < NS; i += 512)
    out[32 + (size_t)(c0 + i) * 32 + b] = (float)idxb[i];
}

__global__ void sentinel_kernel(float* out, int n, float val) {
  int i = blockIdx.x * blockDim.x + threadIdx.x;
  if (i < n) out[i] = val;
}

// ---------------------------------------------------------------------------
extern "C" void kernel_launch(void* const* d_in, const int* in_sizes, int n_in,
                              void* d_out, int out_size, void* d_ws,
                              size_t ws_size, hipStream_t stream) {
  const float* memory = (const float*)d_in[0];
  const int* mask = (const int*)d_in[1];     // bool delivered as int32
  const int* length = (const int*)d_in[2];
  const float* W1  = (const float*)d_in[3];
  const float* b1  = (const float*)d_in[4];
  const float* Wp1 = (const float*)d_in[5];
  const float* bp1 = (const float*)d_in[6];
  const float* Wp2 = (const float*)d_in[7];
  const float* bp2 = (const float*)d_in[8];
  const float* Wih = (const float*)d_in[9];
  const float* Whh = (const float*)d_in[10];
  const float* bih = (const float*)d_in[11];
  const float* bhh = (const float*)d_in[12];
  float* out = (float*)d_out;

  char* ws = (char*)d_ws;
  const size_t o_whc   = 0;                    // 512*128*4  = 262144
  const size_t o_wcomb = 262144;               // 640*128*4  = 327680
  const size_t o_cbias = 589824;               // 640*4      = 2560
  const size_t o_state = 592384;               // -> pad 36864
  const size_t o_pg    = 629248;               // 2047*192*4 = 1572096
  const size_t o_buf   = 2201344;              // chunk buffers

  const size_t per_cs = 32ull * (768 + 3840) * 4;  // 589824
  long long usable = (long long)ws_size - (long long)o_buf;
  int CS = (usable > 0) ? (int)(usable / (long long)per_cs) : 0;
  if (CS > NSTP) CS = NSTP;
  if (CS < 1) {
    float val = -100000.0f - (float)(ws_size >> 20);
    sentinel_kernel<<<(out_size + 255) / 256, 256, 0, stream>>>(out, out_size, val);
    return;
  }

  float* Whc   = (float*)(ws + o_whc);
  float* Wcomb = (float*)(ws + o_wcomb);
  float* cbias = (float*)(ws + o_cbias);
  float* state = (float*)(ws + o_state);
  float* pgbuf = (float*)(ws + o_pg);

  prep_kernel<<<64, 256, 0, stream>>>(Wp1, bp1, Wih, Whh, bih, bhh,
                                      Whc, Wcomb, cbias);
  gumbel_kernel<<<(NSTP * 192 + 255) / 256, 256, 0, stream>>>(pgbuf);

  int nchunks = (NSTP + CS - 1) / CS;
  for (int c = 0; c < nchunks; ++c) {
    int c0 = c * CS;
    int NS = (c0 + CS <= NSTP) ? CS : (NSTP - c0);
    int Mcf = 32 * NS;
    int M6  = Mcf * 6;

    float* cf  = (float*)(ws + o_buf);
    float* exf = cf + (size_t)Mcf * 768;

    // cf = relu(memory_rows @ W1^T + b1): M=32*NS, N=768, K=256
    gemm_kernel<1><<<dim3((Mcf + TM - 1) / TM, 768 / TN), 256, 0, stream>>>(
        memory, W1, 256, b1, cf, 768, Mcf, 256, 1, NS, c0);
    // exf = cf6 @ Wcomb^T + cbias: M=M6, N=640 (p1|g1), K=128
    gemm_kernel<0><<<dim3((M6 + TM - 1) / TM, 640 / TN), 256, 0, stream>>>(
        cf, Wcomb, 128, cbias, exf, 640, M6, 128, 0, NS, c0);
    // scan this chunk
    scan5_kernel<<<BB, 512, 0, stream>>>(exf, pgbuf, mask, length, Wp1, Wp2,
                                         bp2, Whc, state, out, c0, NS,
                                         (c == 0) ? 1 : 0);
  }
}